// Round 13
// baseline (162.132 us; speedup 1.0000x reference)
//
#include <hip/hip_runtime.h>
#include <math.h>

#define N_NODES 50000
#define N_EDGES 1600000
#define IN_CH   512
#define OUT_CH  48
#define XW_LD   64                   // xw row stride in ushorts -> 128B, one cache line
#define N_TILES (N_NODES / 16)       // 3125 row-tiles, exact

#define BSHIFT  6                    // 64 nodes per bucket
#define BNODES  64
#define NB      ((N_NODES + BNODES - 1) / BNODES)   // 782 buckets
#define ETILE   8192                 // edges per bin_edges block
#define CAP     2816                 // max edges per bucket handled by sort
#define CHUNK   64                   // edges per wave in seg_aggregate (divides N_EDGES)

#define BFRAG_SHORTS (16 * 3 * 64 * 8)   // 24576 shorts = 48 KB fragment image of B

typedef __attribute__((ext_vector_type(8))) short bf16x8;
typedef __attribute__((ext_vector_type(4))) float f32x4;

// fp32 -> bf16 (round-to-nearest-even), branch-free
static __device__ inline short f2bf(float x) {
    union { float f; unsigned u; } in; in.f = x;
    unsigned r = in.u + 0x7fffu + ((in.u >> 16) & 1u);
    return (short)(r >> 16);
}
static __device__ inline float bf2f(unsigned v16) {
    union { unsigned u; float f; } o; o.u = v16 << 16; return o.f;
}

// ---------------- Kernel 0: pre-format B into MFMA fragment layout (once) ----------------
__global__ __launch_bounds__(256) void prep_bfrag(const float* __restrict__ w,
                                                  unsigned short* __restrict__ wfrag) {
    int i = blockIdx.x * blockDim.x + threadIdx.x;       // one float4 per thread
    if (i >= IN_CH * OUT_CH / 4) return;
    int flat = i * 4;
    int k   = flat / OUT_CH;
    int col = flat % OUT_CH;
    float4 v = *reinterpret_cast<const float4*>(w + flat);
    int s = k >> 5, j = k & 7, q = (k >> 3) & 3;
    float vv[4] = {v.x, v.y, v.z, v.w};
    #pragma unroll
    for (int c = 0; c < 4; ++c) {
        int cc = col + c;
        int t  = cc >> 4;
        int ln = (cc & 15) | (q << 4);
        wfrag[((s * 3 + t) * 64 + ln) * 8 + j] = (unsigned short)f2bf(vv[c]);
    }
}

// ---------------- Kernel 1: xw = features @ weight via bf16 MFMA ----------------
__global__ __launch_bounds__(256) void gemm_mfma(const float* __restrict__ f,
                                                 const unsigned short* __restrict__ wfrag,
                                                 unsigned short* __restrict__ xw) {
    __shared__ short sBl[BFRAG_SHORTS];   // 48 KB, linear copy of wfrag

    int tid  = threadIdx.x;
    int lane = tid & 63;
    int wid  = tid >> 6;

    {
        const uint4* gw = reinterpret_cast<const uint4*>(wfrag);
        uint4*       sw = reinterpret_cast<uint4*>(sBl);
        #pragma unroll
        for (int i = 0; i < BFRAG_SHORTS / 8 / 256; ++i)   // 12 iterations
            sw[i * 256 + tid] = gw[i * 256 + tid];
    }
    __syncthreads();

    int tile = blockIdx.x * 4 + wid;
    if (tile >= N_TILES) return;

    const bf16x8* sB = reinterpret_cast<const bf16x8*>(sBl);

    int row = tile * 16 + (lane & 15);
    const float* fp = f + (size_t)row * IN_CH + ((lane >> 4) << 3);

    f32x4 acc0 = {0.f, 0.f, 0.f, 0.f};
    f32x4 acc1 = {0.f, 0.f, 0.f, 0.f};
    f32x4 acc2 = {0.f, 0.f, 0.f, 0.f};

    float4 a0[2], a1[2];
    a0[0] = *reinterpret_cast<const float4*>(fp);
    a1[0] = *reinterpret_cast<const float4*>(fp + 4);

    #pragma unroll
    for (int s = 0; s < 16; ++s) {
        const int cb = s & 1, nb = cb ^ 1;
        if (s + 1 < 16) {                                  // prefetch next K-step
            a0[nb] = *reinterpret_cast<const float4*>(fp + (s + 1) * 32);
            a1[nb] = *reinterpret_cast<const float4*>(fp + (s + 1) * 32 + 4);
        }
        bf16x8 a;
        a[0] = f2bf(a0[cb].x); a[1] = f2bf(a0[cb].y);
        a[2] = f2bf(a0[cb].z); a[3] = f2bf(a0[cb].w);
        a[4] = f2bf(a1[cb].x); a[5] = f2bf(a1[cb].y);
        a[6] = f2bf(a1[cb].z); a[7] = f2bf(a1[cb].w);
        bf16x8 b0 = sB[(s * 3 + 0) * 64 + lane];
        bf16x8 b1 = sB[(s * 3 + 1) * 64 + lane];
        bf16x8 b2 = sB[(s * 3 + 2) * 64 + lane];
        acc0 = __builtin_amdgcn_mfma_f32_16x16x32_bf16(a, b0, acc0, 0, 0, 0);
        acc1 = __builtin_amdgcn_mfma_f32_16x16x32_bf16(a, b1, acc1, 0, 0, 0);
        acc2 = __builtin_amdgcn_mfma_f32_16x16x32_bf16(a, b2, acc2, 0, 0, 0);
    }

    unsigned short* orow = xw + (size_t)tile * 16 * XW_LD;
    int c  = lane & 15;
    int r0 = (lane >> 4) * 4;
    #pragma unroll
    for (int r = 0; r < 4; ++r) {
        orow[(size_t)(r0 + r) * XW_LD +  0 + c] = (unsigned short)f2bf(acc0[r]);
        orow[(size_t)(r0 + r) * XW_LD + 16 + c] = (unsigned short)f2bf(acc1[r]);
        orow[(size_t)(r0 + r) * XW_LD + 32 + c] = (unsigned short)f2bf(acc2[r]);
    }
}

// ---------------- Kernel 2: per-bucket histogram (LDS-staged) ----------------
__global__ __launch_bounds__(256) void bucket_hist(const int* __restrict__ dst,
                                                   int* __restrict__ counts) {
    __shared__ int h[NB];
    for (int i = threadIdx.x; i < NB; i += blockDim.x) h[i] = 0;
    __syncthreads();
    for (int e = blockIdx.x * blockDim.x + threadIdx.x; e < N_EDGES;
         e += gridDim.x * blockDim.x)
        atomicAdd(&h[dst[e] >> BSHIFT], 1);
    __syncthreads();
    for (int i = threadIdx.x; i < NB; i += blockDim.x)
        if (h[i]) atomicAdd(&counts[i], h[i]);
}

// ---------------- Kernel 3: exclusive scan over NB buckets (1 block) ----------------
__global__ __launch_bounds__(1024) void bucket_scan(const int* __restrict__ counts,
                                                    int* __restrict__ base,
                                                    int* __restrict__ cursor) {
    __shared__ int sdata[1024];
    int t = threadIdx.x;
    int v = (t < NB) ? counts[t] : 0;
    sdata[t] = v;
    __syncthreads();
    for (int d = 1; d < 1024; d <<= 1) {
        int x = (t >= d) ? sdata[t - d] : 0;
        __syncthreads();
        sdata[t] += x;
        __syncthreads();
    }
    if (t < NB) { int e = sdata[t] - v; base[t] = e; cursor[t] = e; }
}

// ---------------- Kernel 4: LDS-staged binning (coalesced scatter) ----------------
__global__ __launch_bounds__(512) void bin_edges(const int* __restrict__ src,
                                                 const int* __restrict__ dst,
                                                 const float* __restrict__ ew,
                                                 int* __restrict__ cursor,
                                                 int2* __restrict__ epack) {
    __shared__ int   hist[NB];
    __shared__ int   loff[NB];
    __shared__ int   gbase[NB];
    __shared__ int   ssum[512];
    __shared__ int2  buf[ETILE];      // 64 KB
    __shared__ short bkt[ETILE];      // 16 KB

    int tid = threadIdx.x;
    int tileStart = blockIdx.x * ETILE;
    int tileN = N_EDGES - tileStart; if (tileN > ETILE) tileN = ETILE;

    for (int i = tid; i < NB; i += 512) hist[i] = 0;
    __syncthreads();

    // pass A: ranks via LDS histogram (cache dst in registers)
    int rank[ETILE / 512];
    int dreg[ETILE / 512];
    #pragma unroll
    for (int k = 0; k < ETILE / 512; ++k) {
        int e = tileStart + k * 512 + tid;
        dreg[k] = (e < N_EDGES) ? dst[e] : 0;
        rank[k] = (e < N_EDGES) ? atomicAdd(&hist[dreg[k] >> BSHIFT], 1) : 0;
    }
    __syncthreads();

    // reserve global space per bucket
    for (int i = tid; i < NB; i += 512) {
        int c = hist[i];
        gbase[i] = c ? atomicAdd(&cursor[i], c) : 0;
    }

    // exclusive scan of hist -> loff (2 entries per thread)
    int a0 = (2 * tid     < NB) ? hist[2 * tid]     : 0;
    int a1 = (2 * tid + 1 < NB) ? hist[2 * tid + 1] : 0;
    ssum[tid] = a0 + a1;
    __syncthreads();
    for (int d = 1; d < 512; d <<= 1) {
        int x = (tid >= d) ? ssum[tid - d] : 0;
        __syncthreads();
        ssum[tid] += x;
        __syncthreads();
    }
    int excl = ssum[tid] - (a0 + a1);
    if (2 * tid     < NB) loff[2 * tid]     = excl;
    if (2 * tid + 1 < NB) loff[2 * tid + 1] = excl + a0;
    __syncthreads();

    // pass B: stage edges into LDS in bucket order
    #pragma unroll
    for (int k = 0; k < ETILE / 512; ++k) {
        int e = tileStart + k * 512 + tid;
        if (e < N_EDGES) {
            int d = dreg[k];
            int b = d >> BSHIFT;
            int slot = loff[b] + rank[k];
            int2 p;
            p.x = (src[e] & 0xFFFF) | (d << 16);   // src 16b | full dst 16b
            p.y = __float_as_int(ew[e]);
            buf[slot] = p;
            bkt[slot] = (short)b;
        }
    }
    __syncthreads();

    // streaming writeout: consecutive slots -> consecutive global positions
    for (int idx = tid; idx < tileN; idx += 512) {
        int b = bkt[idx];
        epack[gbase[b] + idx - loff[b]] = buf[idx];
    }
}

// ---------------- Kernel 5: in-bucket sort by node ----------------
__global__ __launch_bounds__(256) void sort_bucket(const int* __restrict__ base,
                                                   const int* __restrict__ cursor,
                                                   int2* __restrict__ epack) {
    __shared__ int2  A[CAP];      // 22.5 KB
    __shared__ int2  B[CAP];      // 22.5 KB
    __shared__ short rk[CAP];     // 5.6 KB
    __shared__ int   hist[BNODES];
    __shared__ int   loff[BNODES];

    int b  = blockIdx.x;
    int lo = base[b], hi = cursor[b];
    int len = hi - lo;
    if (len <= 0 || len > CAP) return;   // oversize: leave unsorted (agg still correct)

    int tid = threadIdx.x;
    if (tid < BNODES) hist[tid] = 0;
    for (int i = tid; i < len; i += 256) A[i] = epack[lo + i];
    __syncthreads();

    for (int i = tid; i < len; i += 256) {
        int key = (((unsigned)A[i].x) >> 16) & (BNODES - 1);
        rk[i] = (short)atomicAdd(&hist[key], 1);
    }
    __syncthreads();

    if (tid < BNODES) {           // wave 0: exclusive scan of 64 counters
        int v = hist[tid];
        int s = v;
        #pragma unroll
        for (int d = 1; d < 64; d <<= 1) {
            int t = __shfl_up(s, d);
            if (tid >= d) s += t;
        }
        loff[tid] = s - v;
    }
    __syncthreads();

    for (int i = tid; i < len; i += 256) {
        int key = (((unsigned)A[i].x) >> 16) & (BNODES - 1);
        B[loff[key] + rk[i]] = A[i];
    }
    __syncthreads();

    for (int i = tid; i < len; i += 256) epack[lo + i] = B[i];
}

// ---------------- Kernel 6: segmented reduction over sorted edges ----------------
// One wave per 64-edge chunk, TWO independent half-wave streams. NO shfls,
// NO register arrays: edge metadata is half-uniform, loaded directly as a
// broadcast int2; all pipeline state in macro-generated NAMED registers.
// Schedule keeps one full block of row-gathers + next metadata in flight.
#define LM(k) int2 M##k = ep2[2 * (k) + h];
#define LR(k) unsigned R##k = *reinterpret_cast<const unsigned*>( \
                  xw + (size_t)(M##k.x & 0xFFFF) * XW_LD + (cp << 1));
#define PR(k) { int nd = (int)(((unsigned)M##k.x) >> 16);                        \
                if (nd != cur) {                                                 \
                    if (act) {                                                   \
                        atomicAdd(&out[(size_t)cur * OUT_CH + (cp << 1)    ], ax); \
                        atomicAdd(&out[(size_t)cur * OUT_CH + (cp << 1) + 1], ay); \
                    }                                                            \
                    ax = 0.f; ay = 0.f; cur = nd;                                \
                }                                                                \
                float wf = __int_as_float(M##k.y);                               \
                ax = fmaf(wf, bf2f(R##k & 0xFFFFu), ax);                         \
                ay = fmaf(wf, bf2f(R##k >> 16), ay); }

__global__ __launch_bounds__(256) void seg_aggregate(const int2* __restrict__ epack,
                                                     const unsigned short* __restrict__ xw,
                                                     float* __restrict__ out) {
    int wv   = (blockIdx.x * blockDim.x + threadIdx.x) >> 6;
    int lane = threadIdx.x & 63;
    int base = wv * CHUNK;
    if (base >= N_EDGES) return;          // CHUNK divides N_EDGES exactly
    int h  = lane >> 5;                   // half: 0 -> even edges, 1 -> odd edges
    int cp = lane & 31;                   // channel pair (cp<24 real, rest pad)
    bool act = (cp < 24);
    const int2* ep2 = epack + base;

    float ax = 0.f, ay = 0.f;

    LM(0) LM(1) LM(2) LM(3) LM(4) LM(5) LM(6) LM(7)
    int cur = (int)(((unsigned)M0.x) >> 16);
    LR(0) LR(1) LR(2) LR(3) LR(4) LR(5) LR(6) LR(7)
    LM(8) LM(9) LM(10) LM(11) LM(12) LM(13) LM(14) LM(15)
    LR(8) LR(9) LR(10) LR(11) LR(12) LR(13) LR(14) LR(15)
    LM(16) LM(17) LM(18) LM(19) LM(20) LM(21) LM(22) LM(23)
    PR(0) PR(1) PR(2) PR(3) PR(4) PR(5) PR(6) PR(7)
    LR(16) LR(17) LR(18) LR(19) LR(20) LR(21) LR(22) LR(23)
    LM(24) LM(25) LM(26) LM(27) LM(28) LM(29) LM(30) LM(31)
    PR(8) PR(9) PR(10) PR(11) PR(12) PR(13) PR(14) PR(15)
    LR(24) LR(25) LR(26) LR(27) LR(28) LR(29) LR(30) LR(31)
    PR(16) PR(17) PR(18) PR(19) PR(20) PR(21) PR(22) PR(23)
    PR(24) PR(25) PR(26) PR(27) PR(28) PR(29) PR(30) PR(31)

    if (act) {
        atomicAdd(&out[(size_t)cur * OUT_CH + (cp << 1)    ], ax);
        atomicAdd(&out[(size_t)cur * OUT_CH + (cp << 1) + 1], ay);
    }
}

// ---------------- Kernel 7: bias + log-softmax, in place, wave per node ----------------
__global__ __launch_bounds__(256) void lsm_rows(float* __restrict__ z,
                                                const float* __restrict__ bias) {
    int node = (blockIdx.x * blockDim.x + threadIdx.x) >> 6;
    int lane = threadIdx.x & 63;
    if (node >= N_NODES) return;
    bool ch = (lane < OUT_CH);

    float v = ch ? (z[(size_t)node * OUT_CH + lane] + bias[lane]) : -INFINITY;
    float m = v;
    #pragma unroll
    for (int d = 32; d >= 1; d >>= 1) m = fmaxf(m, __shfl_xor(m, d));
    float e = ch ? expf(v - m) : 0.f;
    float s = e;
    #pragma unroll
    for (int d = 32; d >= 1; d >>= 1) s += __shfl_xor(s, d);
    float lse = m + logf(s);
    if (ch) z[(size_t)node * OUT_CH + lane] = v - lse;
}

extern "C" void kernel_launch(void* const* d_in, const int* in_sizes, int n_in,
                              void* d_out, int out_size, void* d_ws, size_t ws_size,
                              hipStream_t stream) {
    const int*   edge_index = (const int*)d_in[0];
    const float* features   = (const float*)d_in[1];
    const float* eweights   = (const float*)d_in[2];
    const float* weight     = (const float*)d_in[3];
    const float* bias       = (const float*)d_in[4];

    const int* src = edge_index;            // edge_index[0, :]
    const int* dst = edge_index + N_EDGES;  // edge_index[1, :]

    float* out = (float*)d_out;

    // Workspace layout (bytes):
    //   xw (bf16, LD=64) @ 0 : 50000*64*2 = 6,400,000
    //   counts  @ 9,600,000 : NB*4
    //   base    @ 9,608,000 : NB*4
    //   cursor  @ 9,616,000 : NB*4
    //   epack   @ 9,624,000 : 12,800,000   (ends 22,424,000)
    //   wfrag   @ 22,424,000 : 49,152
    char* ws = (char*)d_ws;
    unsigned short* xw    = (unsigned short*)(ws + 0);
    int*   counts = (int*)  (ws + 9600000);
    int*   base   = (int*)  (ws + 9608000);
    int*   cursor = (int*)  (ws + 9616000);
    int2*  epack  = (int2*) (ws + 9624000);
    unsigned short* wfrag = (unsigned short*)(ws + 22424000);

    hipMemsetAsync(counts, 0, NB * sizeof(int), stream);
    hipMemsetAsync(d_out, 0, (size_t)N_NODES * OUT_CH * sizeof(float), stream);

    // 0) pre-format B fragments (once per launch)
    prep_bfrag<<<(IN_CH * OUT_CH / 4 + 255) / 256, 256, 0, stream>>>(weight, wfrag);

    // 1) xw = features @ weight  (bf16 MFMA, bf16 output)
    gemm_mfma<<<(N_TILES + 3) / 4, 256, 0, stream>>>(features, wfrag, xw);

    // 2) bucket binning (coarse, write-coalesced) + in-bucket sort
    bucket_hist<<<256, 256, 0, stream>>>(dst, counts);
    bucket_scan<<<1, 1024, 0, stream>>>(counts, base, cursor);
    bin_edges<<<(N_EDGES + ETILE - 1) / ETILE, 512, 0, stream>>>(src, dst, eweights,
                                                                 cursor, epack);
    sort_bucket<<<NB, 256, 0, stream>>>(base, cursor, epack);

    // 3) segmented reduction (wave per 64-edge chunk, straight-line pipeline)
    {
        int nWaves  = N_EDGES / CHUNK;                 // 25000
        int nBlocks = (nWaves + 3) / 4;                // 6250
        seg_aggregate<<<nBlocks, 256, 0, stream>>>(epack, xw, out);
    }
    // 4) bias + log-softmax
    lsm_rows<<<(N_NODES + 3) / 4, 256, 0, stream>>>(out, bias);
}

// Round 14
// 146.996 us; speedup vs baseline: 1.1030x; 1.1030x over previous
//
#include <hip/hip_runtime.h>
#include <math.h>

#define N_NODES 50000
#define N_EDGES 1600000
#define IN_CH   512
#define OUT_CH  48
#define XW_LD   64                   // xw row stride in ushorts -> 128B, one cache line
#define N_TILES (N_NODES / 16)       // 3125 row-tiles, exact

#define BSHIFT  6                    // 64 nodes per bucket
#define BNODES  64
#define NB      ((N_NODES + BNODES - 1) / BNODES)   // 782 buckets
#define ETILE   8192                 // edges per bin_edges block
#define CAP     2816                 // max edges per bucket handled by sort

#define BFRAG_SHORTS (16 * 3 * 64 * 8)   // 24576 shorts = 48 KB fragment image of B

typedef __attribute__((ext_vector_type(8))) short bf16x8;
typedef __attribute__((ext_vector_type(4))) float f32x4;

// fp32 -> bf16 (round-to-nearest-even), branch-free
static __device__ inline short f2bf(float x) {
    union { float f; unsigned u; } in; in.f = x;
    unsigned r = in.u + 0x7fffu + ((in.u >> 16) & 1u);
    return (short)(r >> 16);
}
static __device__ inline float bf2f(unsigned v16) {
    union { unsigned u; float f; } o; o.u = v16 << 16; return o.f;
}

// ---------------- Kernel 0: pre-format B into MFMA fragment layout (once) ----------------
__global__ __launch_bounds__(256) void prep_bfrag(const float* __restrict__ w,
                                                  unsigned short* __restrict__ wfrag) {
    int i = blockIdx.x * blockDim.x + threadIdx.x;       // one float4 per thread
    if (i >= IN_CH * OUT_CH / 4) return;
    int flat = i * 4;
    int k   = flat / OUT_CH;
    int col = flat % OUT_CH;
    float4 v = *reinterpret_cast<const float4*>(w + flat);
    int s = k >> 5, j = k & 7, q = (k >> 3) & 3;
    float vv[4] = {v.x, v.y, v.z, v.w};
    #pragma unroll
    for (int c = 0; c < 4; ++c) {
        int cc = col + c;
        int t  = cc >> 4;
        int ln = (cc & 15) | (q << 4);
        wfrag[((s * 3 + t) * 64 + ln) * 8 + j] = (unsigned short)f2bf(vv[c]);
    }
}

// ---------------- Kernel 1: xw = features @ weight via bf16 MFMA ----------------
__global__ __launch_bounds__(256) void gemm_mfma(const float* __restrict__ f,
                                                 const unsigned short* __restrict__ wfrag,
                                                 unsigned short* __restrict__ xw) {
    __shared__ short sBl[BFRAG_SHORTS];   // 48 KB, linear copy of wfrag

    int tid  = threadIdx.x;
    int lane = tid & 63;
    int wid  = tid >> 6;

    {
        const uint4* gw = reinterpret_cast<const uint4*>(wfrag);
        uint4*       sw = reinterpret_cast<uint4*>(sBl);
        #pragma unroll
        for (int i = 0; i < BFRAG_SHORTS / 8 / 256; ++i)   // 12 iterations
            sw[i * 256 + tid] = gw[i * 256 + tid];
    }
    __syncthreads();

    int tile = blockIdx.x * 4 + wid;
    if (tile >= N_TILES) return;

    const bf16x8* sB = reinterpret_cast<const bf16x8*>(sBl);

    int row = tile * 16 + (lane & 15);
    const float* fp = f + (size_t)row * IN_CH + ((lane >> 4) << 3);

    f32x4 acc0 = {0.f, 0.f, 0.f, 0.f};
    f32x4 acc1 = {0.f, 0.f, 0.f, 0.f};
    f32x4 acc2 = {0.f, 0.f, 0.f, 0.f};

    float4 a0[2], a1[2];
    a0[0] = *reinterpret_cast<const float4*>(fp);
    a1[0] = *reinterpret_cast<const float4*>(fp + 4);

    #pragma unroll
    for (int s = 0; s < 16; ++s) {
        const int cb = s & 1, nb = cb ^ 1;
        if (s + 1 < 16) {                                  // prefetch next K-step
            a0[nb] = *reinterpret_cast<const float4*>(fp + (s + 1) * 32);
            a1[nb] = *reinterpret_cast<const float4*>(fp + (s + 1) * 32 + 4);
        }
        bf16x8 a;
        a[0] = f2bf(a0[cb].x); a[1] = f2bf(a0[cb].y);
        a[2] = f2bf(a0[cb].z); a[3] = f2bf(a0[cb].w);
        a[4] = f2bf(a1[cb].x); a[5] = f2bf(a1[cb].y);
        a[6] = f2bf(a1[cb].z); a[7] = f2bf(a1[cb].w);
        bf16x8 b0 = sB[(s * 3 + 0) * 64 + lane];
        bf16x8 b1 = sB[(s * 3 + 1) * 64 + lane];
        bf16x8 b2 = sB[(s * 3 + 2) * 64 + lane];
        acc0 = __builtin_amdgcn_mfma_f32_16x16x32_bf16(a, b0, acc0, 0, 0, 0);
        acc1 = __builtin_amdgcn_mfma_f32_16x16x32_bf16(a, b1, acc1, 0, 0, 0);
        acc2 = __builtin_amdgcn_mfma_f32_16x16x32_bf16(a, b2, acc2, 0, 0, 0);
    }

    unsigned short* orow = xw + (size_t)tile * 16 * XW_LD;
    int c  = lane & 15;
    int r0 = (lane >> 4) * 4;
    #pragma unroll
    for (int r = 0; r < 4; ++r) {
        orow[(size_t)(r0 + r) * XW_LD +  0 + c] = (unsigned short)f2bf(acc0[r]);
        orow[(size_t)(r0 + r) * XW_LD + 16 + c] = (unsigned short)f2bf(acc1[r]);
        orow[(size_t)(r0 + r) * XW_LD + 32 + c] = (unsigned short)f2bf(acc2[r]);
    }
}

// ---------------- Kernel 2: per-bucket histogram (LDS-staged) ----------------
__global__ __launch_bounds__(256) void bucket_hist(const int* __restrict__ dst,
                                                   int* __restrict__ counts) {
    __shared__ int h[NB];
    for (int i = threadIdx.x; i < NB; i += blockDim.x) h[i] = 0;
    __syncthreads();
    for (int e = blockIdx.x * blockDim.x + threadIdx.x; e < N_EDGES;
         e += gridDim.x * blockDim.x)
        atomicAdd(&h[dst[e] >> BSHIFT], 1);
    __syncthreads();
    for (int i = threadIdx.x; i < NB; i += blockDim.x)
        if (h[i]) atomicAdd(&counts[i], h[i]);
}

// ---------------- Kernel 3: exclusive scan over NB buckets (1 block) ----------------
__global__ __launch_bounds__(1024) void bucket_scan(const int* __restrict__ counts,
                                                    int* __restrict__ base,
                                                    int* __restrict__ cursor) {
    __shared__ int sdata[1024];
    int t = threadIdx.x;
    int v = (t < NB) ? counts[t] : 0;
    sdata[t] = v;
    __syncthreads();
    for (int d = 1; d < 1024; d <<= 1) {
        int x = (t >= d) ? sdata[t - d] : 0;
        __syncthreads();
        sdata[t] += x;
        __syncthreads();
    }
    if (t < NB) { int e = sdata[t] - v; base[t] = e; cursor[t] = e; }
}

// ---------------- Kernel 4: LDS-staged binning (coalesced scatter) ----------------
__global__ __launch_bounds__(512) void bin_edges(const int* __restrict__ src,
                                                 const int* __restrict__ dst,
                                                 const float* __restrict__ ew,
                                                 int* __restrict__ cursor,
                                                 int2* __restrict__ epack) {
    __shared__ int   hist[NB];
    __shared__ int   loff[NB];
    __shared__ int   gbase[NB];
    __shared__ int   ssum[512];
    __shared__ int2  buf[ETILE];      // 64 KB
    __shared__ short bkt[ETILE];      // 16 KB

    int tid = threadIdx.x;
    int tileStart = blockIdx.x * ETILE;
    int tileN = N_EDGES - tileStart; if (tileN > ETILE) tileN = ETILE;

    for (int i = tid; i < NB; i += 512) hist[i] = 0;
    __syncthreads();

    // pass A: ranks via LDS histogram (cache dst in registers)
    int rank[ETILE / 512];
    int dreg[ETILE / 512];
    #pragma unroll
    for (int k = 0; k < ETILE / 512; ++k) {
        int e = tileStart + k * 512 + tid;
        dreg[k] = (e < N_EDGES) ? dst[e] : 0;
        rank[k] = (e < N_EDGES) ? atomicAdd(&hist[dreg[k] >> BSHIFT], 1) : 0;
    }
    __syncthreads();

    // reserve global space per bucket
    for (int i = tid; i < NB; i += 512) {
        int c = hist[i];
        gbase[i] = c ? atomicAdd(&cursor[i], c) : 0;
    }

    // exclusive scan of hist -> loff (2 entries per thread)
    int a0 = (2 * tid     < NB) ? hist[2 * tid]     : 0;
    int a1 = (2 * tid + 1 < NB) ? hist[2 * tid + 1] : 0;
    ssum[tid] = a0 + a1;
    __syncthreads();
    for (int d = 1; d < 512; d <<= 1) {
        int x = (tid >= d) ? ssum[tid - d] : 0;
        __syncthreads();
        ssum[tid] += x;
        __syncthreads();
    }
    int excl = ssum[tid] - (a0 + a1);
    if (2 * tid     < NB) loff[2 * tid]     = excl;
    if (2 * tid + 1 < NB) loff[2 * tid + 1] = excl + a0;
    __syncthreads();

    // pass B: stage edges into LDS in bucket order
    #pragma unroll
    for (int k = 0; k < ETILE / 512; ++k) {
        int e = tileStart + k * 512 + tid;
        if (e < N_EDGES) {
            int d = dreg[k];
            int b = d >> BSHIFT;
            int slot = loff[b] + rank[k];
            int2 p;
            p.x = (src[e] & 0xFFFF) | (d << 16);   // src 16b | full dst 16b
            p.y = __float_as_int(ew[e]);
            buf[slot] = p;
            bkt[slot] = (short)b;
        }
    }
    __syncthreads();

    // streaming writeout: consecutive slots -> consecutive global positions
    for (int idx = tid; idx < tileN; idx += 512) {
        int b = bkt[idx];
        epack[gbase[b] + idx - loff[b]] = buf[idx];
    }
}

// ---------------- Kernel 5: in-bucket sort by node ----------------
__global__ __launch_bounds__(256) void sort_bucket(const int* __restrict__ base,
                                                   const int* __restrict__ cursor,
                                                   int2* __restrict__ epack) {
    __shared__ int2  A[CAP];      // 22.5 KB
    __shared__ int2  B[CAP];      // 22.5 KB
    __shared__ short rk[CAP];     // 5.6 KB
    __shared__ int   hist[BNODES];
    __shared__ int   loff[BNODES];

    int b  = blockIdx.x;
    int lo = base[b], hi = cursor[b];
    int len = hi - lo;
    if (len <= 0 || len > CAP) return;   // oversize: leave unsorted (agg still correct)

    int tid = threadIdx.x;
    if (tid < BNODES) hist[tid] = 0;
    for (int i = tid; i < len; i += 256) A[i] = epack[lo + i];
    __syncthreads();

    for (int i = tid; i < len; i += 256) {
        int key = (((unsigned)A[i].x) >> 16) & (BNODES - 1);
        rk[i] = (short)atomicAdd(&hist[key], 1);
    }
    __syncthreads();

    if (tid < BNODES) {           // wave 0: exclusive scan of 64 counters
        int v = hist[tid];
        int s = v;
        #pragma unroll
        for (int d = 1; d < 64; d <<= 1) {
            int t = __shfl_up(s, d);
            if (tid >= d) s += t;
        }
        loff[tid] = s - v;
    }
    __syncthreads();

    for (int i = tid; i < len; i += 256) {
        int key = (((unsigned)A[i].x) >> 16) & (BNODES - 1);
        B[loff[key] + rk[i]] = A[i];
    }
    __syncthreads();

    for (int i = tid; i < len; i += 256) epack[lo + i] = B[i];
}

// ---------------- Kernel 6: per-bucket aggregate + bias + log-softmax ----------------
// One block per bucket (exclusive owner of 64 output rows). 4 waves split the
// bucket's edges; register run-accumulation with pipelined wide gathers
// (half-wave streams as r13); run-boundary flushes go to an LDS accumulator
// via ds_add (no global atomics anywhere). Epilogue: bias + log-softmax on the
// LDS tile, plain coalesced stores to out.
#define LM(k) int2 M##k = ep2[2 * (k) + h];
#define LR(k) unsigned R##k = *reinterpret_cast<const unsigned*>( \
                  xw + (size_t)(M##k.x & 0xFFFF) * XW_LD + (cp << 1));
#define PRL(k) { int nd = (int)(((unsigned)M##k.x) >> 16);                 \
                if (nd != cur) {                                           \
                    if (act && cur >= 0) {                                 \
                        atomicAdd(&acc[cur & (BNODES - 1)][cp << 1],       ax); \
                        atomicAdd(&acc[cur & (BNODES - 1)][(cp << 1) + 1], ay); \
                    }                                                      \
                    ax = 0.f; ay = 0.f; cur = nd;                          \
                }                                                          \
                float wf = __int_as_float(M##k.y);                         \
                ax = fmaf(wf, bf2f(R##k & 0xFFFFu), ax);                   \
                ay = fmaf(wf, bf2f(R##k >> 16), ay); }

__global__ __launch_bounds__(256) void bucket_agg_lsm(
        const int* __restrict__ base, const int* __restrict__ cursor,
        const int2* __restrict__ epack, const unsigned short* __restrict__ xw,
        const float* __restrict__ bias, float* __restrict__ out) {
    __shared__ float acc[BNODES][OUT_CH];   // 12 KB

    int b   = blockIdx.x;
    int tid = threadIdx.x, lane = tid & 63, wid = tid >> 6;

    for (int i = tid; i < BNODES * OUT_CH; i += 256)
        reinterpret_cast<float*>(acc)[i] = 0.f;
    __syncthreads();

    int lo = base[b], hi = cursor[b];
    int len = hi - lo;
    int per = (len + 3) >> 2;
    int myLo = lo + wid * per;
    int myHi = myLo + per; if (myHi > hi) myHi = hi;

    int h  = lane >> 5;                   // half: even / odd edges
    int cp = lane & 31;                   // channel pair (cp<24 real)
    bool act = (cp < 24);

    float ax = 0.f, ay = 0.f;
    int cur = -1;

    // main: 64-edge chunks (32 per half), pipelined straight-line schedule
    int i = myLo;
    for (; i + 64 <= myHi; i += 64) {
        const int2* ep2 = epack + i;
        LM(0) LM(1) LM(2) LM(3) LM(4) LM(5) LM(6) LM(7)
        LR(0) LR(1) LR(2) LR(3) LR(4) LR(5) LR(6) LR(7)
        LM(8) LM(9) LM(10) LM(11) LM(12) LM(13) LM(14) LM(15)
        LR(8) LR(9) LR(10) LR(11) LR(12) LR(13) LR(14) LR(15)
        LM(16) LM(17) LM(18) LM(19) LM(20) LM(21) LM(22) LM(23)
        PRL(0) PRL(1) PRL(2) PRL(3) PRL(4) PRL(5) PRL(6) PRL(7)
        LR(16) LR(17) LR(18) LR(19) LR(20) LR(21) LR(22) LR(23)
        LM(24) LM(25) LM(26) LM(27) LM(28) LM(29) LM(30) LM(31)
        PRL(8) PRL(9) PRL(10) PRL(11) PRL(12) PRL(13) PRL(14) PRL(15)
        LR(24) LR(25) LR(26) LR(27) LR(28) LR(29) LR(30) LR(31)
        PRL(16) PRL(17) PRL(18) PRL(19) PRL(20) PRL(21) PRL(22) PRL(23)
        PRL(24) PRL(25) PRL(26) PRL(27) PRL(28) PRL(29) PRL(30) PRL(31)
    }
    // tail: per-edge (same parity split)
    for (int j = i + h; j < myHi; j += 2) {
        int2 M = epack[j];
        int nd = (int)(((unsigned)M.x) >> 16);
        if (nd != cur) {
            if (act && cur >= 0) {
                atomicAdd(&acc[cur & (BNODES - 1)][cp << 1],       ax);
                atomicAdd(&acc[cur & (BNODES - 1)][(cp << 1) + 1], ay);
            }
            ax = 0.f; ay = 0.f; cur = nd;
        }
        unsigned R = *reinterpret_cast<const unsigned*>(
            xw + (size_t)(M.x & 0xFFFF) * XW_LD + (cp << 1));
        float wf = __int_as_float(M.y);
        ax = fmaf(wf, bf2f(R & 0xFFFFu), ax);
        ay = fmaf(wf, bf2f(R >> 16), ay);
    }
    if (act && cur >= 0) {
        atomicAdd(&acc[cur & (BNODES - 1)][cp << 1],       ax);
        atomicAdd(&acc[cur & (BNODES - 1)][(cp << 1) + 1], ay);
    }
    __syncthreads();

    // epilogue: bias + log-softmax per node (16 nodes per wave), plain stores
    bool ch = (lane < OUT_CH);
    float bv = ch ? bias[lane] : 0.f;
    int node0 = b << BSHIFT;
    for (int n = wid; n < BNODES; n += 4) {
        int node = node0 + n;
        if (node >= N_NODES) break;
        float v = ch ? (acc[n][lane] + bv) : -INFINITY;
        float m = v;
        #pragma unroll
        for (int d = 32; d >= 1; d >>= 1) m = fmaxf(m, __shfl_xor(m, d));
        float e = ch ? expf(v - m) : 0.f;
        float s = e;
        #pragma unroll
        for (int d = 32; d >= 1; d >>= 1) s += __shfl_xor(s, d);
        float lse = m + logf(s);
        if (ch) out[(size_t)node * OUT_CH + lane] = v - lse;
    }
}

extern "C" void kernel_launch(void* const* d_in, const int* in_sizes, int n_in,
                              void* d_out, int out_size, void* d_ws, size_t ws_size,
                              hipStream_t stream) {
    const int*   edge_index = (const int*)d_in[0];
    const float* features   = (const float*)d_in[1];
    const float* eweights   = (const float*)d_in[2];
    const float* weight     = (const float*)d_in[3];
    const float* bias       = (const float*)d_in[4];

    const int* src = edge_index;            // edge_index[0, :]
    const int* dst = edge_index + N_EDGES;  // edge_index[1, :]

    float* out = (float*)d_out;

    // Workspace layout (bytes):
    //   xw (bf16, LD=64) @ 0 : 50000*64*2 = 6,400,000
    //   counts  @ 9,600,000 : NB*4
    //   base    @ 9,608,000 : NB*4
    //   cursor  @ 9,616,000 : NB*4
    //   epack   @ 9,624,000 : 12,800,000   (ends 22,424,000)
    //   wfrag   @ 22,424,000 : 49,152
    char* ws = (char*)d_ws;
    unsigned short* xw    = (unsigned short*)(ws + 0);
    int*   counts = (int*)  (ws + 9600000);
    int*   base   = (int*)  (ws + 9608000);
    int*   cursor = (int*)  (ws + 9616000);
    int2*  epack  = (int2*) (ws + 9624000);
    unsigned short* wfrag = (unsigned short*)(ws + 22424000);

    hipMemsetAsync(counts, 0, NB * sizeof(int), stream);

    // 0) pre-format B fragments (once per launch)
    prep_bfrag<<<(IN_CH * OUT_CH / 4 + 255) / 256, 256, 0, stream>>>(weight, wfrag);

    // 1) xw = features @ weight  (bf16 MFMA, bf16 output)
    gemm_mfma<<<(N_TILES + 3) / 4, 256, 0, stream>>>(features, wfrag, xw);

    // 2) bucket binning (coarse, write-coalesced) + in-bucket sort
    bucket_hist<<<256, 256, 0, stream>>>(dst, counts);
    bucket_scan<<<1, 1024, 0, stream>>>(counts, base, cursor);
    bin_edges<<<(N_EDGES + ETILE - 1) / ETILE, 512, 0, stream>>>(src, dst, eweights,
                                                                 cursor, epack);
    sort_bucket<<<NB, 256, 0, stream>>>(base, cursor, epack);

    // 3) per-bucket aggregate + bias + log-softmax (no global atomics)
    bucket_agg_lsm<<<NB, 256, 0, stream>>>(base, cursor, epack, xw, bias, out);
}